// Round 12
// baseline (1055.786 us; speedup 1.0000x reference)
//
#include <hip/hip_runtime.h>
#include <hip/hip_cooperative_groups.h>
#include <hip/hip_fp16.h>
#include <math.h>

namespace cg = cooperative_groups;

// Problem constants (GATv2, 3 layers, H=4 heads, C=64 channels, D=64 in-dim)
#define HC   256   // H*C
#define DD   64
#define CC   64
#define NLAY 3
#define SREP 32          // stats replication for the mega path
#define SSZ  (SREP*128)
#define XSTR 72          // LDS row stride in halves

typedef _Float16 h2 __attribute__((ext_vector_type(2)));
typedef _Float16 h4 __attribute__((ext_vector_type(4)));
typedef _Float16 h8 __attribute__((ext_vector_type(8)));
typedef float    f4 __attribute__((ext_vector_type(4)));
typedef float    f2 __attribute__((ext_vector_type(2)));

// ===========================================================================
// MEGA: whole pipeline in ONE cooperative kernel (kills ~13 dispatch gaps).
// ===========================================================================
struct MegaArgs {
    const float* x0;
    const int*   srcA; const int* dstA;
    const float* Wl; const float* bl;
    const float* Wr; const float* br;
    const float* att; const float* cb;
    const float* gw; const float* gs; const float* gb;
    __half* xl; __half* xr;
    float*  hbuf;
    int* counts; int* cursor; int* rowptr; int* csr;
    float* stats;          // NLAY * SREP * 128
    __half* Wh;            // NLAY*2*256*64 fp16 pre-converted weights
    int* btot; int* ebase; // scan temporaries
    float* outp;
    int n, e;
};

__global__ __launch_bounds__(256, 4) void mega(MegaArgs A) {
    cg::grid_group grid = cg::this_grid();
    const int t    = threadIdx.x;
    const int bid  = blockIdx.x;
    const int nb   = gridDim.x;
    const int gtid = bid * 256 + t;
    const int gsz  = nb * 256;
    const int n = A.n, e = A.e, tot = A.e + A.n;

    __shared__ union {
        struct { _Float16 xs[64 * XSTR]; float na[64]; float nbf[64]; } p;
        struct { int ls[256]; } s;
        struct { float sacc[128]; } a;
    } sh;

    // ---- P0: zero counts/stats; convert W fp32->fp16 -------------------
    for (int i = gtid; i < n; i += gsz) A.counts[i] = 0;
    for (int i = gtid; i < NLAY * SSZ; i += gsz) A.stats[i] = 0.f;
    for (int i = gtid; i < NLAY * 2 * HC * DD; i += gsz) {
        int lm = i >> 14, off = i & 16383;         // 16384 = 256*64
        int L = lm >> 1, mat = lm & 1;
        const float* sw = mat ? A.Wr : A.Wl;
        A.Wh[i] = __float2half(sw[L * 16384 + off]);
    }
    grid.sync();

    // ---- P1: histogram of destinations (self-loops appended) -----------
    for (int i = gtid; i < tot; i += gsz) {
        int d = (i < e) ? A.dstA[i] : (i - e);
        atomicAdd(&A.counts[d], 1);
    }
    grid.sync();

    // ---- P2: per-block scan of counts -----------------------------------
    const int SB = (n + 255) >> 8;                  // 98 blocks active
    if (bid < SB) {
        int i = bid * 256 + t;
        int val = (i < n) ? A.counts[i] : 0;
        sh.s.ls[t] = val;
        __syncthreads();
        for (int off = 1; off < 256; off <<= 1) {
            int v = (t >= off) ? sh.s.ls[t - off] : 0;
            __syncthreads();
            sh.s.ls[t] += v;
            __syncthreads();
        }
        if (i < n) A.cursor[i] = sh.s.ls[t] - val;  // excl. within block
        if (t == 255) A.btot[bid] = sh.s.ls[255];
    }
    grid.sync();

    // ---- P3: block 0 scans the block totals -----------------------------
    if (bid == 0) {
        int v2 = (t < SB) ? A.btot[t] : 0;
        sh.s.ls[t] = v2;
        __syncthreads();
        for (int off = 1; off < 256; off <<= 1) {
            int v = (t >= off) ? sh.s.ls[t - off] : 0;
            __syncthreads();
            sh.s.ls[t] += v;
            __syncthreads();
        }
        if (t < SB) A.ebase[t] = sh.s.ls[t] - v2;
    }
    grid.sync();

    // ---- P4: finalize rowptr + cursor(=starts) --------------------------
    if (bid < SB) {
        int i = bid * 256 + t;
        if (i < n) {
            int st = A.cursor[i] + A.ebase[bid];
            A.rowptr[i] = st;
            A.cursor[i] = st;
        }
    }
    if (gtid == 0) A.rowptr[n] = tot;
    grid.sync();

    // ---- P5: fill CSR (no sync after: covered by proj's grid.sync) ------
    for (int i = gtid; i < tot; i += gsz) {
        int s_, d;
        if (i < e) { s_ = A.srcA[i]; d = A.dstA[i]; }
        else       { s_ = d = i - e; }
        int slot = atomicAdd(&A.cursor[d], 1);
        A.csr[slot] = s_;
    }

    const int wave = t >> 6;
    const int l    = t & 63;
    const int NT    = (n + 63) >> 6;
    const int NJOBS = NT * 2;

    for (int L = 0; L < NLAY; ++L) {
        // ---------------- proj phase ----------------
        const float* xin = (L == 0) ? A.x0 : A.hbuf;
        const float* stL = (L == 0) ? nullptr : A.stats + (size_t)(L - 1) * SSZ;
        const int Lp = (L == 0) ? 0 : L - 1;
        if (t < 64) {
            float a = 1.f, b = 0.f;
            if (stL) {
                float sm = 0.f, sq = 0.f;
                for (int r = 0; r < SREP; ++r) {
                    sm += stL[r * 128 + t];
                    sq += stL[r * 128 + 64 + t];
                }
                float inv_n = 1.f / (float)n;
                float mu = sm * inv_n, eh2 = sq * inv_n;
                float al = A.gs[Lp * CC + t];
                float var = eh2 - 2.f * al * mu * mu + al * al * mu * mu;
                float rstd = rsqrtf(var + 1e-5f);
                a = A.gw[Lp * CC + t] * rstd;
                b = A.gb[Lp * CC + t] - al * mu * a;
            }
            sh.p.na[t] = a; sh.p.nbf[t] = b;
        }
        __syncthreads();

        for (int job = bid; job < NJOBS; job += nb) {
            const int mat = job & 1;
            const int n0  = (job >> 1) * 64;
            const _Float16* Whm = (const _Float16*)A.Wh + ((size_t)L * 2 + mat) * (HC * DD);
            const float* bsel = (mat ? A.br : A.bl) + L * HC;
            __half*      osel = mat ? A.xr : A.xl;
            __syncthreads();                       // xs safe to overwrite
            {   // stage x tile (fp32 -> norm -> fp16)
                const float* xb = xin + (size_t)n0 * DD;
                const int limit = (n - n0) * DD;
                #pragma unroll
                for (int it = 0; it < 4; ++it) {
                    int f = (it * 256 + t) * 4;
                    float4 v = make_float4(0.f, 0.f, 0.f, 0.f);
                    if (f + 3 < limit) v = *(const float4*)(xb + f);
                    else {
                        float tmp[4] = {0.f, 0.f, 0.f, 0.f};
                        for (int q = 0; q < 4; ++q) if (f + q < limit) tmp[q] = xb[f + q];
                        v = make_float4(tmp[0], tmp[1], tmp[2], tmp[3]);
                    }
                    int d = f & 63;
                    const float4 a4 = *(const float4*)&sh.p.na[d];
                    const float4 b4 = *(const float4*)&sh.p.nbf[d];
                    h4 hv;
                    hv.x = (_Float16)fmaf(v.x, a4.x, b4.x);
                    hv.y = (_Float16)fmaf(v.y, a4.y, b4.y);
                    hv.z = (_Float16)fmaf(v.z, a4.z, b4.z);
                    hv.w = (_Float16)fmaf(v.w, a4.w, b4.w);
                    *(h4*)&sh.p.xs[(f >> 6) * XSTR + d] = hv;
                }
            }
            __syncthreads();
            const int m = l & 15, q = l >> 4;
            const _Float16* arow = sh.p.xs + (wave * 16 + m) * XSTR + q * 8;
            const h8 A0 = *(const h8*)arow;
            const h8 A1 = *(const h8*)(arow + 32);
            f4 acc[16];
            #pragma unroll
            for (int ct = 0; ct < 16; ++ct) {
                const _Float16* brow = Whm + (ct * 16 + m) * DD + q * 8;  // L2-hot
                const h8 B0 = *(const h8*)brow;
                const h8 B1 = *(const h8*)(brow + 32);
                f4 c = {0.f, 0.f, 0.f, 0.f};
                c = __builtin_amdgcn_mfma_f32_16x16x32_f16(A0, B0, c, 0, 0, 0);
                c = __builtin_amdgcn_mfma_f32_16x16x32_f16(A1, B1, c, 0, 0, 0);
                acc[ct] = c;
            }
            #pragma unroll
            for (int ct = 0; ct < 16; ++ct) {
                int ch = ct * 16 + m;
                float bv = bsel[ch];
                #pragma unroll
                for (int r = 0; r < 4; ++r) {
                    int node = n0 + wave * 16 + q * 4 + r;
                    if (node < n)
                        osel[(size_t)node * HC + ch] = __float2half(acc[ct][r] + bv);
                }
            }
        }
        grid.sync();

        // ---------------- attn phase (R8 core) + block-agg stats ---------
        if (t < 128) sh.a.sacc[t] = 0.f;
        __syncthreads();
        {
            const int e2 = l >> 5;
            const int hh = (l >> 3) & 3;
            const int co = l & 7;
            const int choff = hh * CC + co * 8;
            const float* attL = A.att + L * HC;
            const float* cbL  = A.cb + L * CC;
            h2 at2[4];
            {
                float4 a0 = *(const float4*)(attL + choff);
                float4 a1 = *(const float4*)(attL + choff + 4);
                at2[0] = (h2){(_Float16)a0.x, (_Float16)a0.y};
                at2[1] = (h2){(_Float16)a0.z, (_Float16)a0.w};
                at2[2] = (h2){(_Float16)a1.x, (_Float16)a1.y};
                at2[3] = (h2){(_Float16)a1.z, (_Float16)a1.w};
            }
            const _Float16 k02 = (_Float16)0.2f;

            for (int v = bid * 4 + wave; v < n; v += nb * 4) {
                h2 xr2[4];
                *(uint4*)xr2 = *(const uint4*)(A.xr + (size_t)v * HC + choff);
                const int rs = A.rowptr[v];
                const int re = A.rowptr[v + 1];
                float s = 0.f;
                f2 acc2[4];
                #pragma unroll
                for (int q = 0; q < 4; ++q) acc2[q] = (f2){0.f, 0.f};

                #define CLAMPI(i) (((i) < re) ? (i) : rs)
                uint4 r0 = *(const uint4*)(A.xl + (size_t)A.csr[CLAMPI(rs + e2)]     * HC + choff);
                uint4 r1 = *(const uint4*)(A.xl + (size_t)A.csr[CLAMPI(rs + 2 + e2)] * HC + choff);
                int jn = A.csr[CLAMPI(rs + 4 + e2)];

                for (int k = rs; k < re; k += 4) {
                    {   // stage A: pair k
                        const uint4 cur = r0;
                        r0 = *(const uint4*)(A.xl + (size_t)jn * HC + choff);
                        jn = A.csr[CLAMPI(k + 6 + e2)];
                        const bool valid = (k + e2) < re;
                        const h2* xh = (const h2*)&cur;
                        h2 d2 = (h2){(_Float16)0.f, (_Float16)0.f};
                        #pragma unroll
                        for (int q = 0; q < 4; ++q) {
                            h2 tt = xh[q] + xr2[q];
                            h2 lk = __builtin_elementwise_max(tt, tt * k02);
                            d2 += lk * at2[q];
                        }
                        float p = (float)d2.x + (float)d2.y;
                        p += __shfl_xor(p, 1, 64);
                        p += __shfl_xor(p, 2, 64);
                        p += __shfl_xor(p, 4, 64);
                        float pe = valid ? __expf(p) : 0.f;
                        s += pe;
                        const f2 pe2 = (f2){pe, pe};
                        #pragma unroll
                        for (int q = 0; q < 4; ++q)
                            acc2[q] += pe2 * (f2){(float)xh[q].x, (float)xh[q].y};
                    }
                    {   // stage B: pair k+2
                        const uint4 cur = r1;
                        r1 = *(const uint4*)(A.xl + (size_t)jn * HC + choff);
                        jn = A.csr[CLAMPI(k + 8 + e2)];
                        const bool valid = (k + 2 + e2) < re;
                        const h2* xh = (const h2*)&cur;
                        h2 d2 = (h2){(_Float16)0.f, (_Float16)0.f};
                        #pragma unroll
                        for (int q = 0; q < 4; ++q) {
                            h2 tt = xh[q] + xr2[q];
                            h2 lk = __builtin_elementwise_max(tt, tt * k02);
                            d2 += lk * at2[q];
                        }
                        float p = (float)d2.x + (float)d2.y;
                        p += __shfl_xor(p, 1, 64);
                        p += __shfl_xor(p, 2, 64);
                        p += __shfl_xor(p, 4, 64);
                        float pe = valid ? __expf(p) : 0.f;
                        s += pe;
                        const f2 pe2 = (f2){pe, pe};
                        #pragma unroll
                        for (int q = 0; q < 4; ++q)
                            acc2[q] += pe2 * (f2){(float)xh[q].x, (float)xh[q].y};
                    }
                }
                #undef CLAMPI

                s += __shfl_xor(s, 32, 64);
                const float inv = 1.f / s;
                float out8[8];
                #pragma unroll
                for (int q = 0; q < 8; ++q) {
                    float av = (q & 1) ? acc2[q >> 1].y : acc2[q >> 1].x;
                    float a = av + __shfl_xor(av, 32, 64);
                    a *= inv;
                    a += __shfl_xor(a, 8, 64);
                    a += __shfl_xor(a, 16, 64);
                    out8[q] = 0.25f * a;
                }
                if (l < 8) {
                    const float4 cb0 = *(const float4*)(cbL + co * 8);
                    const float4 cb1 = *(const float4*)(cbL + co * 8 + 4);
                    float4 o0 = make_float4(out8[0] + cb0.x, out8[1] + cb0.y,
                                            out8[2] + cb0.z, out8[3] + cb0.w);
                    float4 o1 = make_float4(out8[4] + cb1.x, out8[5] + cb1.y,
                                            out8[6] + cb1.z, out8[7] + cb1.w);
                    float* op = A.hbuf + (size_t)v * CC + co * 8;
                    *(float4*)op       = o0;
                    *(float4*)(op + 4) = o1;
                    const float* v0 = (const float*)&o0;
                    const float* v1 = (const float*)&o1;
                    #pragma unroll
                    for (int j = 0; j < 4; ++j) {
                        atomicAdd(&sh.a.sacc[co * 8 + j],          v0[j]);
                        atomicAdd(&sh.a.sacc[64 + co * 8 + j],     v0[j] * v0[j]);
                        atomicAdd(&sh.a.sacc[co * 8 + 4 + j],      v1[j]);
                        atomicAdd(&sh.a.sacc[64 + co * 8 + 4 + j], v1[j] * v1[j]);
                    }
                }
            }
        }
        __syncthreads();
        if (t < 128)
            atomicAdd(&A.stats[(size_t)L * SSZ + (bid & (SREP - 1)) * 128 + t],
                      sh.a.sacc[t]);
        grid.sync();
    }

    // ---------------- final GraphNorm ----------------
    {
        const float* stL = A.stats + (size_t)(NLAY - 1) * SSZ;
        if (t < 64) {
            float sm = 0.f, sq = 0.f;
            for (int r = 0; r < SREP; ++r) {
                sm += stL[r * 128 + t];
                sq += stL[r * 128 + 64 + t];
            }
            float inv_n = 1.f / (float)n;
            float mu = sm * inv_n, eh2 = sq * inv_n;
            float al = A.gs[(NLAY - 1) * CC + t];
            float var = eh2 - 2.f * al * mu * mu + al * al * mu * mu;
            float rstd = rsqrtf(var + 1e-5f);
            float a = A.gw[(NLAY - 1) * CC + t] * rstd;
            sh.p.na[t]  = a;
            sh.p.nbf[t] = A.gb[(NLAY - 1) * CC + t] - al * mu * a;
        }
        __syncthreads();
        int total = n * CC;
        for (int idx = gtid; idx < total; idx += gsz) {
            int c = idx & 63;
            A.outp[idx] = fmaf(A.hbuf[idx], sh.p.na[c], sh.p.nbf[c]);
        }
    }
}

// ===========================================================================
// FALLBACK: R11's proven multi-kernel path (used only if coop launch fails)
// ===========================================================================
__global__ __launch_bounds__(256) void zero_kernel(int* counts, int* cursor,
                                                   float* stats, int n) {
    int i = blockIdx.x * 256 + threadIdx.x;
    if (i < n) { counts[i] = 0; cursor[i] = 0; }
    if (i < NLAY * 128) stats[i] = 0.f;
}
__global__ __launch_bounds__(256) void count_kernel(const int* dstArr, int* counts,
                                                    int e, int n) {
    int i = blockIdx.x * 256 + threadIdx.x;
    if (i >= e + n) return;
    int d = (i < e) ? dstArr[i] : (i - e);
    atomicAdd(&counts[d], 1);
}
#define SCAN_CAP 25600
__global__ __launch_bounds__(1024) void scan_kernel(const int* counts, int* rowptr, int n) {
    __shared__ short lsh[SCAN_CAP];
    __shared__ int ss[1024];
    __shared__ int tb[1024];
    const int t = threadIdx.x;
    for (int i = t; i < n; i += 1024) lsh[i] = (short)counts[i];
    __syncthreads();
    const int chunk = (n + 1023) >> 10;
    const int base = t * chunk;
    const int end  = (base + chunk < n) ? base + chunk : n;
    int local = 0;
    for (int i = base; i < end; ++i) local += lsh[i];
    ss[t] = local;
    __syncthreads();
    for (int off = 1; off < 1024; off <<= 1) {
        int v = (t >= off) ? ss[t - off] : 0;
        __syncthreads();
        ss[t] += v;
        __syncthreads();
    }
    tb[t] = ss[t] - local;
    { int run = 0;
      for (int i = base; i < end; ++i) { int c = lsh[i]; lsh[i] = (short)run; run += c; } }
    __syncthreads();
    for (int i = t; i < n; i += 1024) rowptr[i] = tb[i / chunk] + (int)lsh[i];
    if (t == 1023) rowptr[n] = ss[1023];
}
__global__ __launch_bounds__(256) void fill_kernel(const int* srcArr, const int* dstArr,
                                                   const int* rowptr, int* cursor,
                                                   int* csr_src, int e, int n) {
    int i = blockIdx.x * 256 + threadIdx.x;
    if (i >= e + n) return;
    int s, d;
    if (i < e) { s = srcArr[i]; d = dstArr[i]; }
    else       { s = d = i - e; }
    int slot = rowptr[d] + atomicAdd(&cursor[d], 1);
    csr_src[slot] = s;
}
__global__ __launch_bounds__(256) void proj_kernel(const float* x, const float* Wl,
    const float* bl, const float* Wr, const float* br, __half* xl, __half* xr, int n,
    const float* stats, const float* pgw, const float* pgs, const float* pgb) {
    __shared__ _Float16 xs[64 * XSTR];
    __shared__ _Float16 ws[256 * XSTR];
    __shared__ float nrm_a[64], nrm_b[64];
    const int t  = threadIdx.x;
    const int n0 = blockIdx.x * 64;
    const float* Wsel = blockIdx.y ? Wr : Wl;
    const float* bsel = blockIdx.y ? br : bl;
    __half*      osel = blockIdx.y ? xr : xl;
    if (t < 64) {
        float a = 1.f, b = 0.f;
        if (stats) {
            float inv_n = 1.0f / (float)n;
            float mu  = stats[t] * inv_n;
            float eh2 = stats[64 + t] * inv_n;
            float al  = pgs[t];
            float var = eh2 - 2.f * al * mu * mu + al * al * mu * mu;
            float rstd = rsqrtf(var + 1e-5f);
            a = pgw[t] * rstd;
            b = pgb[t] - al * mu * a;
        }
        nrm_a[t] = a; nrm_b[t] = b;
    }
    __syncthreads();
    {
        const float* xb = x + (size_t)n0 * DD;
        const int limit = (n - n0) * DD;
        #pragma unroll
        for (int it = 0; it < 4; ++it) {
            int f = (it * 256 + t) * 4;
            float4 v = make_float4(0.f, 0.f, 0.f, 0.f);
            if (f + 3 < limit) v = *(const float4*)(xb + f);
            else {
                float tmp[4] = {0.f, 0.f, 0.f, 0.f};
                for (int q = 0; q < 4; ++q) if (f + q < limit) tmp[q] = xb[f + q];
                v = make_float4(tmp[0], tmp[1], tmp[2], tmp[3]);
            }
            int d = f & 63;
            const float4 a4 = *(const float4*)&nrm_a[d];
            const float4 b4 = *(const float4*)&nrm_b[d];
            h4 hv;
            hv.x = (_Float16)fmaf(v.x, a4.x, b4.x);
            hv.y = (_Float16)fmaf(v.y, a4.y, b4.y);
            hv.z = (_Float16)fmaf(v.z, a4.z, b4.z);
            hv.w = (_Float16)fmaf(v.w, a4.w, b4.w);
            *(h4*)&xs[(f >> 6) * XSTR + d] = hv;
        }
    }
    {
        #pragma unroll
        for (int it = 0; it < 16; ++it) {
            int f = (it * 256 + t) * 4;
            float4 v = *(const float4*)(Wsel + f);
            h4 hv = { (_Float16)v.x, (_Float16)v.y, (_Float16)v.z, (_Float16)v.w };
            *(h4*)&ws[(f >> 6) * XSTR + (f & 63)] = hv;
        }
    }
    __syncthreads();
    const int w = t >> 6, lane = t & 63, m = lane & 15, q = lane >> 4;
    const _Float16* arow = xs + (w * 16 + m) * XSTR + q * 8;
    const h8 A0 = *(const h8*)arow;
    const h8 A1 = *(const h8*)(arow + 32);
    f4 acc[16];
    #pragma unroll
    for (int ct = 0; ct < 16; ++ct) {
        const _Float16* brow = ws + (ct * 16 + m) * XSTR + q * 8;
        const h8 B0 = *(const h8*)brow;
        const h8 B1 = *(const h8*)(brow + 32);
        f4 c = {0.f, 0.f, 0.f, 0.f};
        c = __builtin_amdgcn_mfma_f32_16x16x32_f16(A0, B0, c, 0, 0, 0);
        c = __builtin_amdgcn_mfma_f32_16x16x32_f16(A1, B1, c, 0, 0, 0);
        acc[ct] = c;
    }
    #pragma unroll
    for (int ct = 0; ct < 16; ++ct) {
        int ch = ct * 16 + m;
        float bv = bsel[ch];
        #pragma unroll
        for (int r = 0; r < 4; ++r) {
            int node = n0 + w * 16 + q * 4 + r;
            if (node < n) osel[(size_t)node * HC + ch] = __float2half(acc[ct][r] + bv);
        }
    }
}
__global__ __launch_bounds__(256) void attn_kernel(const __half* xl, const __half* xr,
    const float* att, const float* conv_bias, const int* rowptr, const int* csr_src,
    float* h_out, int n) {
    const int wave = threadIdx.x >> 6;
    const int l    = threadIdx.x & 63;
    const int v    = blockIdx.x * 4 + wave;
    if (v >= n) return;
    const int e2 = l >> 5, h = (l >> 3) & 3, co = l & 7;
    const int choff = h * CC + co * 8;
    h2 xr2[4];
    *(uint4*)xr2 = *(const uint4*)(xr + (size_t)v * HC + choff);
    h2 at2[4];
    {
        const float* ap = att + choff;
        float4 a0 = *(const float4*)(ap);
        float4 a1 = *(const float4*)(ap + 4);
        at2[0] = (h2){(_Float16)a0.x, (_Float16)a0.y};
        at2[1] = (h2){(_Float16)a0.z, (_Float16)a0.w};
        at2[2] = (h2){(_Float16)a1.x, (_Float16)a1.y};
        at2[3] = (h2){(_Float16)a1.z, (_Float16)a1.w};
    }
    const _Float16 k02 = (_Float16)0.2f;
    const int rs = rowptr[v], re = rowptr[v + 1];
    float s = 0.f;
    f2 acc2[4];
    #pragma unroll
    for (int q = 0; q < 4; ++q) acc2[q] = (f2){0.f, 0.f};
    #define CLAMPI(i) (((i) < re) ? (i) : rs)
    uint4 r0 = *(const uint4*)(xl + (size_t)csr_src[CLAMPI(rs + e2)]     * HC + choff);
    uint4 r1 = *(const uint4*)(xl + (size_t)csr_src[CLAMPI(rs + 2 + e2)] * HC + choff);
    int jn = csr_src[CLAMPI(rs + 4 + e2)];
    for (int k = rs; k < re; k += 4) {
        {
            const uint4 cur = r0;
            r0 = *(const uint4*)(xl + (size_t)jn * HC + choff);
            jn = csr_src[CLAMPI(k + 6 + e2)];
            const bool valid = (k + e2) < re;
            const h2* xh = (const h2*)&cur;
            h2 d2 = (h2){(_Float16)0.f, (_Float16)0.f};
            #pragma unroll
            for (int q = 0; q < 4; ++q) {
                h2 tt = xh[q] + xr2[q];
                h2 lk = __builtin_elementwise_max(tt, tt * k02);
                d2 += lk * at2[q];
            }
            float p = (float)d2.x + (float)d2.y;
            p += __shfl_xor(p, 1, 64);
            p += __shfl_xor(p, 2, 64);
            p += __shfl_xor(p, 4, 64);
            float pe = valid ? __expf(p) : 0.f;
            s += pe;
            const f2 pe2 = (f2){pe, pe};
            #pragma unroll
            for (int q = 0; q < 4; ++q)
                acc2[q] += pe2 * (f2){(float)xh[q].x, (float)xh[q].y};
        }
        {
            const uint4 cur = r1;
            r1 = *(const uint4*)(xl + (size_t)jn * HC + choff);
            jn = csr_src[CLAMPI(k + 8 + e2)];
            const bool valid = (k + 2 + e2) < re;
            const h2* xh = (const h2*)&cur;
            h2 d2 = (h2){(_Float16)0.f, (_Float16)0.f};
            #pragma unroll
            for (int q = 0; q < 4; ++q) {
                h2 tt = xh[q] + xr2[q];
                h2 lk = __builtin_elementwise_max(tt, tt * k02);
                d2 += lk * at2[q];
            }
            float p = (float)d2.x + (float)d2.y;
            p += __shfl_xor(p, 1, 64);
            p += __shfl_xor(p, 2, 64);
            p += __shfl_xor(p, 4, 64);
            float pe = valid ? __expf(p) : 0.f;
            s += pe;
            const f2 pe2 = (f2){pe, pe};
            #pragma unroll
            for (int q = 0; q < 4; ++q)
                acc2[q] += pe2 * (f2){(float)xh[q].x, (float)xh[q].y};
        }
    }
    #undef CLAMPI
    s += __shfl_xor(s, 32, 64);
    const float inv = 1.f / s;
    float out8[8];
    #pragma unroll
    for (int q = 0; q < 8; ++q) {
        float av = (q & 1) ? acc2[q >> 1].y : acc2[q >> 1].x;
        float a = av + __shfl_xor(av, 32, 64);
        a *= inv;
        a += __shfl_xor(a, 8, 64);
        a += __shfl_xor(a, 16, 64);
        out8[q] = 0.25f * a;
    }
    if (l < 8) {
        const float4 cb0 = *(const float4*)(conv_bias + co * 8);
        const float4 cb1 = *(const float4*)(conv_bias + co * 8 + 4);
        float4 o0 = make_float4(out8[0] + cb0.x, out8[1] + cb0.y,
                                out8[2] + cb0.z, out8[3] + cb0.w);
        float4 o1 = make_float4(out8[4] + cb1.x, out8[5] + cb1.y,
                                out8[6] + cb1.z, out8[7] + cb1.w);
        float* op = h_out + (size_t)v * CC + co * 8;
        *(float4*)op       = o0;
        *(float4*)(op + 4) = o1;
    }
}
__global__ __launch_bounds__(256) void stats_kernel(const float* h, float* stats, int n) {
    int t = threadIdx.x;
    int c = t & 63, r = t >> 6;
    float s = 0.f, s2 = 0.f;
    for (int node = blockIdx.x * 4 + r; node < n; node += gridDim.x * 4) {
        float v = h[node * CC + c];
        s += v; s2 += v * v;
    }
    __shared__ float l1[256], l2[256];
    l1[t] = s; l2[t] = s2;
    __syncthreads();
    if (t < 64) {
        s  = l1[t] + l1[64 + t] + l1[128 + t] + l1[192 + t];
        s2 = l2[t] + l2[64 + t] + l2[128 + t] + l2[192 + t];
        atomicAdd(&stats[c], s);
        atomicAdd(&stats[64 + c], s2);
    }
}
__global__ __launch_bounds__(256) void norm_kernel(const float* h, const float* stats,
    const float* gw, const float* gs, const float* gb, float* out, int n) {
    __shared__ float na[64], nb[64];
    int t = threadIdx.x;
    if (t < 64) {
        float inv_n = 1.0f / (float)n;
        float mu  = stats[t] * inv_n;
        float eh2 = stats[64 + t] * inv_n;
        float a   = gs[t];
        float var = eh2 - 2.f * a * mu * mu + a * a * mu * mu;
        float rstd = rsqrtf(var + 1e-5f);
        na[t] = gw[t] * rstd;
        nb[t] = gb[t] - a * mu * gw[t] * rstd;
    }
    __syncthreads();
    int c = t & 63;
    float w = na[c], b = nb[c];
    int total = n * CC;
    for (int idx = blockIdx.x * 256 + t; idx < total; idx += gridDim.x * 256)
        out[idx] = fmaf(h[idx], w, b);
}

// ===========================================================================
extern "C" void kernel_launch(void* const* d_in, const int* in_sizes, int n_in,
                              void* d_out, int out_size, void* d_ws, size_t ws_size,
                              hipStream_t stream) {
    const float* x0  = (const float*)d_in[0];
    const int*   ei  = (const int*)d_in[1];
    const float* Wl  = (const float*)d_in[2];
    const float* bl  = (const float*)d_in[3];
    const float* Wr  = (const float*)d_in[4];
    const float* br  = (const float*)d_in[5];
    const float* att = (const float*)d_in[6];
    const float* cb  = (const float*)d_in[7];
    const float* gw  = (const float*)d_in[8];
    const float* gs  = (const float*)d_in[9];
    const float* gb  = (const float*)d_in[10];

    const int n = in_sizes[0] / DD;      // 25000
    const int e = in_sizes[1] / 2;       // 400000
    const int* srcArr = ei;
    const int* dstArr = ei + e;

    char* w = (char*)d_ws;
    auto alloc = [&](size_t bytes) -> char* {
        char* p = w;
        w += (bytes + 255) & ~(size_t)255;
        return p;
    };
    __half* xl    = (__half*)alloc((size_t)n * HC * 2);
    __half* xr    = (__half*)alloc((size_t)n * HC * 2);
    float* hbuf   = (float*)alloc((size_t)n * CC * 4);
    int*   counts = (int*)  alloc((size_t)n * 4);
    int*   cursor = (int*)  alloc((size_t)n * 4);
    int*   rowptr = (int*)  alloc((size_t)(n + 1) * 4);
    int*   csr    = (int*)  alloc((size_t)(e + n + 2) * 4);
    float* stats  = (float*)alloc((size_t)NLAY * SSZ * 4);
    __half* Wh    = (__half*)alloc((size_t)NLAY * 2 * HC * DD * 2);
    int*   btot   = (int*)  alloc(256 * 4);
    int*   ebase  = (int*)  alloc(256 * 4);

    MegaArgs margs = { x0, srcArr, dstArr, Wl, bl, Wr, br, att, cb, gw, gs, gb,
                       xl, xr, hbuf, counts, cursor, rowptr, csr, stats, Wh,
                       btot, ebase, (float*)d_out, n, e };

    int nbpc = 0;
    hipError_t occ = hipOccupancyMaxActiveBlocksPerMultiprocessor(&nbpc, mega, 256, 0);
    if (occ != hipSuccess || nbpc < 1) nbpc = 1;
    int gridsz = nbpc * 256;               // 256 CUs on MI355X
    if (gridsz > 2048) gridsz = 2048;
    void* kargs[] = { &margs };
    hipError_t rc = hipLaunchCooperativeKernel((void*)mega, dim3(gridsz), dim3(256),
                                               kargs, 0, stream);
    if (rc == hipSuccess) return;

    // ---- fallback: proven R11 multi-kernel path ----
    const int tot = e + n;
    hipLaunchKernelGGL(zero_kernel,  dim3((n + 255) / 256),   dim3(256), 0, stream,
                       counts, cursor, stats, n);
    hipLaunchKernelGGL(count_kernel, dim3((tot + 255) / 256), dim3(256), 0, stream,
                       dstArr, counts, e, n);
    hipLaunchKernelGGL(scan_kernel,  dim3(1), dim3(1024), 0, stream,
                       counts, rowptr, n);
    hipLaunchKernelGGL(fill_kernel,  dim3((tot + 255) / 256), dim3(256), 0, stream,
                       srcArr, dstArr, rowptr, cursor, csr, e, n);
    for (int L = 0; L < NLAY; ++L) {
        const float* xin = (L == 0) ? x0 : hbuf;
        const int Lp = (L == 0) ? 0 : L - 1;
        const float* st = (L == 0) ? nullptr : stats + (size_t)Lp * 128;
        hipLaunchKernelGGL(proj_kernel, dim3((n + 63) / 64, 2), dim3(256), 0, stream,
                           xin, Wl + (size_t)L * HC * DD, bl + L * HC,
                           Wr + (size_t)L * HC * DD, br + L * HC, xl, xr, n,
                           st, gw + Lp * CC, gs + Lp * CC, gb + Lp * CC);
        hipLaunchKernelGGL(attn_kernel, dim3((n + 3) / 4), dim3(256), 0, stream,
                           xl, xr, att + L * HC, cb + L * CC, rowptr, csr, hbuf, n);
        hipLaunchKernelGGL(stats_kernel, dim3(128), dim3(256), 0, stream,
                           hbuf, stats + (size_t)L * 128, n);
    }
    hipLaunchKernelGGL(norm_kernel, dim3(512), dim3(256), 0, stream,
                       hbuf, stats + (size_t)(NLAY - 1) * 128, gw + (NLAY - 1) * CC,
                       gs + (NLAY - 1) * CC, gb + (NLAY - 1) * CC,
                       (float*)d_out, n);
}

// Round 13
// 368.655 us; speedup vs baseline: 2.8639x; 2.8639x over previous
//
#include <hip/hip_runtime.h>
#include <hip/hip_fp16.h>
#include <math.h>

// Problem constants (GATv2, 3 layers, H=4 heads, C=64 channels, D=64 in-dim)
#define HC   256   // H*C
#define DD   64
#define CC   64
#define NLAY 3

typedef _Float16 h2 __attribute__((ext_vector_type(2)));
typedef _Float16 h4 __attribute__((ext_vector_type(4)));
typedef _Float16 h8 __attribute__((ext_vector_type(8)));
typedef float    f4 __attribute__((ext_vector_type(4)));
typedef float    f2 __attribute__((ext_vector_type(2)));

#define XSTR 72   // LDS row stride in halves: 144B = 16B-aligned, 2-way-free banks

// ---------------------------------------------------------------------------
// zero counts/cursor/stats (ws is poisoned 0xAA before every call)
__global__ __launch_bounds__(256) void zero_kernel(int* __restrict__ counts,
                                                   int* __restrict__ cursor,
                                                   float* __restrict__ stats,
                                                   int n) {
    int i = blockIdx.x * 256 + threadIdx.x;
    if (i < n) { counts[i] = 0; cursor[i] = 0; }
    if (i < NLAY * 128) stats[i] = 0.f;
}

// histogram of destination nodes (self-loops appended implicitly)
__global__ __launch_bounds__(256) void count_kernel(const int* __restrict__ dstArr,
                                                    int* __restrict__ counts,
                                                    int e, int n) {
    int i = blockIdx.x * 256 + threadIdx.x;
    if (i >= e + n) return;
    int d = (i < e) ? dstArr[i] : (i - e);
    atomicAdd(&counts[d], 1);
}

// single-block exclusive scan -> rowptr[0..n]; counts staged as short in LDS
#define SCAN_CAP 25600
__global__ __launch_bounds__(1024) void scan_kernel(const int* __restrict__ counts,
                                                    int* __restrict__ rowptr, int n) {
    __shared__ short lsh[SCAN_CAP];
    __shared__ int ss[1024];
    __shared__ int tb[1024];
    const int t = threadIdx.x;
    for (int i = t; i < n; i += 1024) lsh[i] = (short)counts[i];
    __syncthreads();
    const int chunk = (n + 1023) >> 10;
    const int base = t * chunk;
    const int end  = (base + chunk < n) ? base + chunk : n;
    int local = 0;
    for (int i = base; i < end; ++i) local += lsh[i];
    ss[t] = local;
    __syncthreads();
    for (int off = 1; off < 1024; off <<= 1) {
        int v = (t >= off) ? ss[t - off] : 0;
        __syncthreads();
        ss[t] += v;
        __syncthreads();
    }
    tb[t] = ss[t] - local;
    { int run = 0;
      for (int i = base; i < end; ++i) { int c = lsh[i]; lsh[i] = (short)run; run += c; } }
    __syncthreads();
    for (int i = t; i < n; i += 1024)
        rowptr[i] = tb[i / chunk] + (int)lsh[i];
    if (t == 1023) rowptr[n] = ss[1023];
}

// scatter edge sources into CSR slots grouped by destination
__global__ __launch_bounds__(256) void fill_kernel(const int* __restrict__ srcArr,
                                                   const int* __restrict__ dstArr,
                                                   const int* __restrict__ rowptr,
                                                   int* __restrict__ cursor,
                                                   int* __restrict__ csr_src,
                                                   int e, int n) {
    int i = blockIdx.x * 256 + threadIdx.x;
    if (i >= e + n) return;
    int s, d;
    if (i < e) { s = srcArr[i]; d = dstArr[i]; }
    else       { s = d = i - e; }
    int slot = rowptr[d] + atomicAdd(&cursor[d], 1);
    csr_src[slot] = s;
}

// ---------------------------------------------------------------------------
// MFMA projection: out = x @ W^T + b, fp16 in/out, fp32 accumulate.
// grid (ceil(n/64), 2): y=0 -> Wl/bl -> xl ; y=1 -> Wr/br -> xr.
// Fused GraphNorm of the INPUT (prev layer stats; nullptr -> identity).
__global__ __launch_bounds__(256) void proj_kernel(const float* __restrict__ x,
                                                   const float* __restrict__ Wl,
                                                   const float* __restrict__ bl,
                                                   const float* __restrict__ Wr,
                                                   const float* __restrict__ br,
                                                   __half* __restrict__ xl,
                                                   __half* __restrict__ xr, int n,
                                                   const float* __restrict__ stats,
                                                   const float* __restrict__ pgw,
                                                   const float* __restrict__ pgs,
                                                   const float* __restrict__ pgb) {
    __shared__ _Float16 xs[64 * XSTR];
    __shared__ _Float16 ws[256 * XSTR];
    __shared__ float nrm_a[64], nrm_b[64];
    const int t  = threadIdx.x;
    const int n0 = blockIdx.x * 64;
    const float* Wsel = blockIdx.y ? Wr : Wl;
    const float* bsel = blockIdx.y ? br : bl;
    __half*      osel = blockIdx.y ? xr : xl;

    if (t < 64) {
        float a = 1.f, b = 0.f;
        if (stats) {
            float inv_n = 1.0f / (float)n;
            float mu  = stats[t] * inv_n;
            float eh2 = stats[64 + t] * inv_n;
            float al  = pgs[t];
            float var = eh2 - 2.f * al * mu * mu + al * al * mu * mu;
            float rstd = rsqrtf(var + 1e-5f);
            a = pgw[t] * rstd;
            b = pgb[t] - al * mu * a;
        }
        nrm_a[t] = a; nrm_b[t] = b;
    }
    __syncthreads();

    {   // stage x tile (fp32 -> norm -> fp16), coalesced float4
        const float* xb = x + (size_t)n0 * DD;
        const int limit = (n - n0) * DD;
        #pragma unroll
        for (int it = 0; it < 4; ++it) {
            int f = (it * 256 + t) * 4;
            float4 v = make_float4(0.f, 0.f, 0.f, 0.f);
            if (f + 3 < limit) v = *(const float4*)(xb + f);
            else {
                float tmp[4] = {0.f, 0.f, 0.f, 0.f};
                for (int q = 0; q < 4; ++q) if (f + q < limit) tmp[q] = xb[f + q];
                v = make_float4(tmp[0], tmp[1], tmp[2], tmp[3]);
            }
            int d = f & 63;
            const float4 a4 = *(const float4*)&nrm_a[d];
            const float4 b4 = *(const float4*)&nrm_b[d];
            h4 hv;
            hv.x = (_Float16)fmaf(v.x, a4.x, b4.x);
            hv.y = (_Float16)fmaf(v.y, a4.y, b4.y);
            hv.z = (_Float16)fmaf(v.z, a4.z, b4.z);
            hv.w = (_Float16)fmaf(v.w, a4.w, b4.w);
            *(h4*)&xs[(f >> 6) * XSTR + d] = hv;
        }
    }
    {   // stage W (fp32 -> fp16)
        #pragma unroll
        for (int it = 0; it < 16; ++it) {
            int f = (it * 256 + t) * 4;
            float4 v = *(const float4*)(Wsel + f);
            h4 hv = { (_Float16)v.x, (_Float16)v.y, (_Float16)v.z, (_Float16)v.w };
            *(h4*)&ws[(f >> 6) * XSTR + (f & 63)] = hv;
        }
    }
    __syncthreads();

    const int w = t >> 6, lane = t & 63, m = lane & 15, q = lane >> 4;
    const _Float16* arow = xs + (w * 16 + m) * XSTR + q * 8;
    const h8 A0 = *(const h8*)arow;
    const h8 A1 = *(const h8*)(arow + 32);
    f4 acc[16];
    #pragma unroll
    for (int ct = 0; ct < 16; ++ct) {
        const _Float16* brow = ws + (ct * 16 + m) * XSTR + q * 8;
        const h8 B0 = *(const h8*)brow;
        const h8 B1 = *(const h8*)(brow + 32);
        f4 c = {0.f, 0.f, 0.f, 0.f};
        c = __builtin_amdgcn_mfma_f32_16x16x32_f16(A0, B0, c, 0, 0, 0);
        c = __builtin_amdgcn_mfma_f32_16x16x32_f16(A1, B1, c, 0, 0, 0);
        acc[ct] = c;
    }
    #pragma unroll
    for (int ct = 0; ct < 16; ++ct) {
        int ch = ct * 16 + m;
        float bv = bsel[ch];
        #pragma unroll
        for (int r = 0; r < 4; ++r) {
            int node = n0 + w * 16 + q * 4 + r;
            if (node < n)
                osel[(size_t)node * HC + ch] = __float2half(acc[ct][r] + bv);
        }
    }
}

// ---------------------------------------------------------------------------
// per-node attention, ONE wave per node, TWO edges per pair-stage, DEPTH-4
// pipeline in NAMED registers r0..r3 (8 edges in flight; R8 had 4).
// lane l = e2*32 + h*8 + co : edge-slot e2, head h, channel-octet co (8 ch).
// No stats fusion (R9 LDS+barrier and R10 global-atomic variants both lost).
__global__ __launch_bounds__(256) void attn_kernel(const __half* __restrict__ xl,
                                                   const __half* __restrict__ xr,
                                                   const float* __restrict__ att,
                                                   const float* __restrict__ conv_bias,
                                                   const int* __restrict__ rowptr,
                                                   const int* __restrict__ csr_src,
                                                   float* __restrict__ h_out, int n) {
    const int wave = threadIdx.x >> 6;
    const int l    = threadIdx.x & 63;
    const int v    = blockIdx.x * 4 + wave;
    if (v >= n) return;

    const int e2 = l >> 5;
    const int h  = (l >> 3) & 3;
    const int co = l & 7;
    const int choff = h * CC + co * 8;

    h2 xr2[4];
    *(uint4*)xr2 = *(const uint4*)(xr + (size_t)v * HC + choff);
    h2 at2[4];
    {
        const float* ap = att + choff;
        float4 a0 = *(const float4*)(ap);
        float4 a1 = *(const float4*)(ap + 4);
        at2[0] = (h2){(_Float16)a0.x, (_Float16)a0.y};
        at2[1] = (h2){(_Float16)a0.z, (_Float16)a0.w};
        at2[2] = (h2){(_Float16)a1.x, (_Float16)a1.y};
        at2[3] = (h2){(_Float16)a1.z, (_Float16)a1.w};
    }
    const _Float16 k02 = (_Float16)0.2f;

    const int rs = rowptr[v];
    const int re = rowptr[v + 1];

    float s = 0.f;
    f2 acc2[4];
    #pragma unroll
    for (int q = 0; q < 4; ++q) acc2[q] = (f2){0.f, 0.f};

    #define CLAMPI(i) (((i) < re) ? (i) : rs)

    uint4 r0 = *(const uint4*)(xl + (size_t)csr_src[CLAMPI(rs + e2)]     * HC + choff);
    uint4 r1 = *(const uint4*)(xl + (size_t)csr_src[CLAMPI(rs + 2 + e2)] * HC + choff);
    uint4 r2 = *(const uint4*)(xl + (size_t)csr_src[CLAMPI(rs + 4 + e2)] * HC + choff);
    uint4 r3 = *(const uint4*)(xl + (size_t)csr_src[CLAMPI(rs + 6 + e2)] * HC + choff);
    int jn = csr_src[CLAMPI(rs + 8 + e2)];

    // one pair-stage: consume rb, refill it for pair (k+8), advance jn chain
    #define STAGE(rb, koff)                                                     \
    {                                                                           \
        const uint4 cur = rb;                                                   \
        rb = *(const uint4*)(xl + (size_t)jn * HC + choff);                     \
        jn = csr_src[CLAMPI(k + (koff) + 10 + e2)];                             \
        const bool valid = (k + (koff) + e2) < re;                              \
        const h2* xh = (const h2*)&cur;                                         \
        h2 d2 = (h2){(_Float16)0.f, (_Float16)0.f};                             \
        _Pragma("unroll")                                                       \
        for (int q = 0; q < 4; ++q) {                                           \
            h2 tt = xh[q] + xr2[q];                                             \
            h2 lk = __builtin_elementwise_max(tt, tt * k02);                    \
            d2 += lk * at2[q];                                                  \
        }                                                                       \
        float p = (float)d2.x + (float)d2.y;                                    \
        p += __shfl_xor(p, 1, 64);                                              \
        p += __shfl_xor(p, 2, 64);                                              \
        p += __shfl_xor(p, 4, 64);                                              \
        float pe = valid ? __expf(p) : 0.f;                                     \
        s += pe;                                                                \
        const f2 pe2 = (f2){pe, pe};                                            \
        _Pragma("unroll")                                                       \
        for (int q = 0; q < 4; ++q)                                             \
            acc2[q] += pe2 * (f2){(float)xh[q].x, (float)xh[q].y};              \
    }

    for (int k = rs; k < re; k += 8) {
        STAGE(r0, 0)
        STAGE(r1, 2)
        STAGE(r2, 4)
        STAGE(r3, 6)
    }
    #undef STAGE
    #undef CLAMPI

    // combine edge slots, normalize per head, then head-mean
    s += __shfl_xor(s, 32, 64);
    const float inv = 1.f / s;                          // deg>=1 (self-loop)
    float out8[8];
    #pragma unroll
    for (int q = 0; q < 8; ++q) {
        float av = (q & 1) ? acc2[q >> 1].y : acc2[q >> 1].x;
        float a = av + __shfl_xor(av, 32, 64);
        a *= inv;
        a += __shfl_xor(a, 8, 64);
        a += __shfl_xor(a, 16, 64);
        out8[q] = 0.25f * a;
    }
    if (l < 8) {
        const float4 cb0 = *(const float4*)(conv_bias + co * 8);
        const float4 cb1 = *(const float4*)(conv_bias + co * 8 + 4);
        float4 o0 = make_float4(out8[0] + cb0.x, out8[1] + cb0.y,
                                out8[2] + cb0.z, out8[3] + cb0.w);
        float4 o1 = make_float4(out8[4] + cb1.x, out8[5] + cb1.y,
                                out8[6] + cb1.z, out8[7] + cb1.w);
        float* op = h_out + (size_t)v * CC + co * 8;
        *(float4*)op       = o0;
        *(float4*)(op + 4) = o1;
    }
}

// ---------------------------------------------------------------------------
// per-channel sum / sumsq over nodes (hierarchical, 128 blocks, 16K atomics)
__global__ __launch_bounds__(256) void stats_kernel(const float* __restrict__ h,
                                                    float* __restrict__ stats, int n) {
    int t = threadIdx.x;
    int c = t & 63, r = t >> 6;
    float s = 0.f, s2 = 0.f;
    for (int node = blockIdx.x * 4 + r; node < n; node += gridDim.x * 4) {
        float v = h[node * CC + c];
        s += v; s2 += v * v;
    }
    __shared__ float l1[256], l2[256];
    l1[t] = s; l2[t] = s2;
    __syncthreads();
    if (t < 64) {
        s  = l1[t] + l1[64 + t] + l1[128 + t] + l1[192 + t];
        s2 = l2[t] + l2[64 + t] + l2[128 + t] + l2[192 + t];
        atomicAdd(&stats[c], s);
        atomicAdd(&stats[64 + c], s2);
    }
}

// ---------------------------------------------------------------------------
// GraphNorm (final layer only): x = (h - alpha*mu) * rsqrt(var+eps) * w + b
__global__ __launch_bounds__(256) void norm_kernel(const float* __restrict__ h,
                                                   const float* __restrict__ stats,
                                                   const float* __restrict__ gw,
                                                   const float* __restrict__ gs,
                                                   const float* __restrict__ gb,
                                                   float* __restrict__ out, int n) {
    __shared__ float na[64], nb[64];
    int t = threadIdx.x;
    if (t < 64) {
        float inv_n = 1.0f / (float)n;
        float mu  = stats[t] * inv_n;
        float eh2 = stats[64 + t] * inv_n;
        float a   = gs[t];
        float var = eh2 - 2.f * a * mu * mu + a * a * mu * mu;
        float rstd = rsqrtf(var + 1e-5f);
        na[t] = gw[t] * rstd;
        nb[t] = gb[t] - a * mu * gw[t] * rstd;
    }
    __syncthreads();
    int c = t & 63;
    float w = na[c], b = nb[c];
    int total = n * CC;
    for (int idx = blockIdx.x * 256 + t; idx < total; idx += gridDim.x * 256)
        out[idx] = fmaf(h[idx], w, b);
}

// ---------------------------------------------------------------------------
extern "C" void kernel_launch(void* const* d_in, const int* in_sizes, int n_in,
                              void* d_out, int out_size, void* d_ws, size_t ws_size,
                              hipStream_t stream) {
    const float* x0  = (const float*)d_in[0];
    const int*   ei  = (const int*)d_in[1];
    const float* Wl  = (const float*)d_in[2];
    const float* bl  = (const float*)d_in[3];
    const float* Wr  = (const float*)d_in[4];
    const float* br  = (const float*)d_in[5];
    const float* att = (const float*)d_in[6];
    const float* cb  = (const float*)d_in[7];
    const float* gw  = (const float*)d_in[8];
    const float* gs  = (const float*)d_in[9];
    const float* gb  = (const float*)d_in[10];

    const int n = in_sizes[0] / DD;      // 25000
    const int e = in_sizes[1] / 2;       // 400000
    const int* srcArr = ei;
    const int* dstArr = ei + e;

    char* w = (char*)d_ws;
    auto alloc = [&](size_t bytes) -> char* {
        char* p = w;
        w += (bytes + 255) & ~(size_t)255;
        return p;
    };
    __half* xl    = (__half*)alloc((size_t)n * HC * 2);
    __half* xr    = (__half*)alloc((size_t)n * HC * 2);
    float* hbuf   = (float*)alloc((size_t)n * CC * 4);
    int*   counts = (int*)  alloc((size_t)n * 4);
    int*   cursor = (int*)  alloc((size_t)n * 4);
    int*   rowptr = (int*)  alloc((size_t)(n + 1) * 4);
    int*   csr    = (int*)  alloc((size_t)(e + n + 2) * 4);
    float* stats  = (float*)alloc(NLAY * 128 * 4);

    const int tot = e + n;
    hipLaunchKernelGGL(zero_kernel,  dim3((n + 255) / 256),   dim3(256), 0, stream,
                       counts, cursor, stats, n);
    hipLaunchKernelGGL(count_kernel, dim3((tot + 255) / 256), dim3(256), 0, stream,
                       dstArr, counts, e, n);
    hipLaunchKernelGGL(scan_kernel,  dim3(1), dim3(1024), 0, stream,
                       counts, rowptr, n);
    hipLaunchKernelGGL(fill_kernel,  dim3((tot + 255) / 256), dim3(256), 0, stream,
                       srcArr, dstArr, rowptr, cursor, csr, e, n);

    for (int L = 0; L < NLAY; ++L) {
        const float* xin = (L == 0) ? x0 : hbuf;
        const int Lp = (L == 0) ? 0 : L - 1;
        const float* st = (L == 0) ? nullptr : stats + (size_t)Lp * 128;
        hipLaunchKernelGGL(proj_kernel, dim3((n + 63) / 64, 2), dim3(256), 0, stream,
                           xin, Wl + (size_t)L * HC * DD, bl + L * HC,
                           Wr + (size_t)L * HC * DD, br + L * HC, xl, xr, n,
                           st, gw + Lp * CC, gs + Lp * CC, gb + Lp * CC);
        hipLaunchKernelGGL(attn_kernel, dim3((n + 3) / 4), dim3(256), 0, stream,
                           xl, xr, att + L * HC, cb + L * CC, rowptr, csr, hbuf, n);
        hipLaunchKernelGGL(stats_kernel, dim3(128), dim3(256), 0, stream,
                           hbuf, stats + (size_t)L * 128, n);
    }
    hipLaunchKernelGGL(norm_kernel, dim3(512), dim3(256), 0, stream,
                       hbuf, stats + (size_t)(NLAY - 1) * 128, gw + (NLAY - 1) * CC,
                       gs + (NLAY - 1) * CC, gb + (NLAY - 1) * CC,
                       (float*)d_out, n);
}

// Round 14
// 357.532 us; speedup vs baseline: 2.9530x; 1.0311x over previous
//
#include <hip/hip_runtime.h>
#include <hip/hip_fp16.h>
#include <math.h>

// Problem constants (GATv2, 3 layers, H=4 heads, C=64 channels, D=64 in-dim)
#define HC   256   // H*C
#define DD   64
#define CC   64
#define NLAY 3

typedef _Float16 h2 __attribute__((ext_vector_type(2)));
typedef _Float16 h4 __attribute__((ext_vector_type(4)));
typedef _Float16 h8 __attribute__((ext_vector_type(8)));
typedef float    f4 __attribute__((ext_vector_type(4)));
typedef float    f2 __attribute__((ext_vector_type(2)));

#define XSTR 72   // LDS row stride in halves: 144B = 16B-aligned, 2-way-free banks

// ---------------------------------------------------------------------------
// zero counts/cursor/stats (ws is poisoned 0xAA before every call)
__global__ __launch_bounds__(256) void zero_kernel(int* __restrict__ counts,
                                                   int* __restrict__ cursor,
                                                   float* __restrict__ stats,
                                                   int n) {
    int i = blockIdx.x * 256 + threadIdx.x;
    if (i < n) { counts[i] = 0; cursor[i] = 0; }
    if (i < NLAY * 128) stats[i] = 0.f;
}

// histogram of destination nodes (self-loops appended implicitly)
__global__ __launch_bounds__(256) void count_kernel(const int* __restrict__ dstArr,
                                                    int* __restrict__ counts,
                                                    int e, int n) {
    int i = blockIdx.x * 256 + threadIdx.x;
    if (i >= e + n) return;
    int d = (i < e) ? dstArr[i] : (i - e);
    atomicAdd(&counts[d], 1);
}

// single-block exclusive scan -> rowptr[0..n]; counts staged as short in LDS
#define SCAN_CAP 25600
__global__ __launch_bounds__(1024) void scan_kernel(const int* __restrict__ counts,
                                                    int* __restrict__ rowptr, int n) {
    __shared__ short lsh[SCAN_CAP];
    __shared__ int ss[1024];
    __shared__ int tb[1024];
    const int t = threadIdx.x;
    for (int i = t; i < n; i += 1024) lsh[i] = (short)counts[i];
    __syncthreads();
    const int chunk = (n + 1023) >> 10;
    const int base = t * chunk;
    const int end  = (base + chunk < n) ? base + chunk : n;
    int local = 0;
    for (int i = base; i < end; ++i) local += lsh[i];
    ss[t] = local;
    __syncthreads();
    for (int off = 1; off < 1024; off <<= 1) {
        int v = (t >= off) ? ss[t - off] : 0;
        __syncthreads();
        ss[t] += v;
        __syncthreads();
    }
    tb[t] = ss[t] - local;
    { int run = 0;
      for (int i = base; i < end; ++i) { int c = lsh[i]; lsh[i] = (short)run; run += c; } }
    __syncthreads();
    for (int i = t; i < n; i += 1024)
        rowptr[i] = tb[i / chunk] + (int)lsh[i];
    if (t == 1023) rowptr[n] = ss[1023];
}

// scatter edge sources into CSR slots grouped by destination
__global__ __launch_bounds__(256) void fill_kernel(const int* __restrict__ srcArr,
                                                   const int* __restrict__ dstArr,
                                                   const int* __restrict__ rowptr,
                                                   int* __restrict__ cursor,
                                                   int* __restrict__ csr_src,
                                                   int e, int n) {
    int i = blockIdx.x * 256 + threadIdx.x;
    if (i >= e + n) return;
    int s, d;
    if (i < e) { s = srcArr[i]; d = dstArr[i]; }
    else       { s = d = i - e; }
    int slot = rowptr[d] + atomicAdd(&cursor[d], 1);
    csr_src[slot] = s;
}

// ---------------------------------------------------------------------------
// MFMA projection: out = x @ W^T + b, fp16 in/out, fp32 accumulate.
// grid (ceil(n/64), 2): y=0 -> Wl/bl -> xl ; y=1 -> Wr/br -> xr.
// Fused GraphNorm of the INPUT (prev layer stats; nullptr -> identity).
__global__ __launch_bounds__(256) void proj_kernel(const float* __restrict__ x,
                                                   const float* __restrict__ Wl,
                                                   const float* __restrict__ bl,
                                                   const float* __restrict__ Wr,
                                                   const float* __restrict__ br,
                                                   __half* __restrict__ xl,
                                                   __half* __restrict__ xr, int n,
                                                   const float* __restrict__ stats,
                                                   const float* __restrict__ pgw,
                                                   const float* __restrict__ pgs,
                                                   const float* __restrict__ pgb) {
    __shared__ _Float16 xs[64 * XSTR];
    __shared__ _Float16 ws[256 * XSTR];
    __shared__ float nrm_a[64], nrm_b[64];
    const int t  = threadIdx.x;
    const int n0 = blockIdx.x * 64;
    const float* Wsel = blockIdx.y ? Wr : Wl;
    const float* bsel = blockIdx.y ? br : bl;
    __half*      osel = blockIdx.y ? xr : xl;

    if (t < 64) {
        float a = 1.f, b = 0.f;
        if (stats) {
            float inv_n = 1.0f / (float)n;
            float mu  = stats[t] * inv_n;
            float eh2 = stats[64 + t] * inv_n;
            float al  = pgs[t];
            float var = eh2 - 2.f * al * mu * mu + al * al * mu * mu;
            float rstd = rsqrtf(var + 1e-5f);
            a = pgw[t] * rstd;
            b = pgb[t] - al * mu * a;
        }
        nrm_a[t] = a; nrm_b[t] = b;
    }
    __syncthreads();

    {   // stage x tile (fp32 -> norm -> fp16), coalesced float4
        const float* xb = x + (size_t)n0 * DD;
        const int limit = (n - n0) * DD;
        #pragma unroll
        for (int it = 0; it < 4; ++it) {
            int f = (it * 256 + t) * 4;
            float4 v = make_float4(0.f, 0.f, 0.f, 0.f);
            if (f + 3 < limit) v = *(const float4*)(xb + f);
            else {
                float tmp[4] = {0.f, 0.f, 0.f, 0.f};
                for (int q = 0; q < 4; ++q) if (f + q < limit) tmp[q] = xb[f + q];
                v = make_float4(tmp[0], tmp[1], tmp[2], tmp[3]);
            }
            int d = f & 63;
            const float4 a4 = *(const float4*)&nrm_a[d];
            const float4 b4 = *(const float4*)&nrm_b[d];
            h4 hv;
            hv.x = (_Float16)fmaf(v.x, a4.x, b4.x);
            hv.y = (_Float16)fmaf(v.y, a4.y, b4.y);
            hv.z = (_Float16)fmaf(v.z, a4.z, b4.z);
            hv.w = (_Float16)fmaf(v.w, a4.w, b4.w);
            *(h4*)&xs[(f >> 6) * XSTR + d] = hv;
        }
    }
    {   // stage W (fp32 -> fp16)
        #pragma unroll
        for (int it = 0; it < 16; ++it) {
            int f = (it * 256 + t) * 4;
            float4 v = *(const float4*)(Wsel + f);
            h4 hv = { (_Float16)v.x, (_Float16)v.y, (_Float16)v.z, (_Float16)v.w };
            *(h4*)&ws[(f >> 6) * XSTR + (f & 63)] = hv;
        }
    }
    __syncthreads();

    const int w = t >> 6, lane = t & 63, m = lane & 15, q = lane >> 4;
    const _Float16* arow = xs + (w * 16 + m) * XSTR + q * 8;
    const h8 A0 = *(const h8*)arow;
    const h8 A1 = *(const h8*)(arow + 32);
    f4 acc[16];
    #pragma unroll
    for (int ct = 0; ct < 16; ++ct) {
        const _Float16* brow = ws + (ct * 16 + m) * XSTR + q * 8;
        const h8 B0 = *(const h8*)brow;
        const h8 B1 = *(const h8*)(brow + 32);
        f4 c = {0.f, 0.f, 0.f, 0.f};
        c = __builtin_amdgcn_mfma_f32_16x16x32_f16(A0, B0, c, 0, 0, 0);
        c = __builtin_amdgcn_mfma_f32_16x16x32_f16(A1, B1, c, 0, 0, 0);
        acc[ct] = c;
    }
    #pragma unroll
    for (int ct = 0; ct < 16; ++ct) {
        int ch = ct * 16 + m;
        float bv = bsel[ch];
        #pragma unroll
        for (int r = 0; r < 4; ++r) {
            int node = n0 + w * 16 + q * 4 + r;
            if (node < n)
                osel[(size_t)node * HC + ch] = __float2half(acc[ct][r] + bv);
        }
    }
}

// ---------------------------------------------------------------------------
// per-node attention, ONE wave per node, TWO edges per pair-stage, depth-2
// pipeline in NAMED registers (R8/R11-proven core). NEW: packed-fp16
// accumulators (pk_fma_f16) — drops 8 cvt + 4 f32-fma per edge (~20% diet).
// Safe: pe>0 (monotone sums, no cancellation), |terms|<~60, |sum|<~200
// << 65504; normalized by same-magnitude s -> rel err ~2e-3.
// lane l = e2*32 + h*8 + co : edge-slot e2, head h, channel-octet co (8 ch).
__global__ __launch_bounds__(256) void attn_kernel(const __half* __restrict__ xl,
                                                   const __half* __restrict__ xr,
                                                   const float* __restrict__ att,
                                                   const float* __restrict__ conv_bias,
                                                   const int* __restrict__ rowptr,
                                                   const int* __restrict__ csr_src,
                                                   float* __restrict__ h_out, int n) {
    const int wave = threadIdx.x >> 6;
    const int l    = threadIdx.x & 63;
    const int v    = blockIdx.x * 4 + wave;
    if (v >= n) return;

    const int e2 = l >> 5;
    const int h  = (l >> 3) & 3;
    const int co = l & 7;
    const int choff = h * CC + co * 8;

    h2 xr2[4];
    *(uint4*)xr2 = *(const uint4*)(xr + (size_t)v * HC + choff);
    h2 at2[4];
    {
        const float* ap = att + choff;
        float4 a0 = *(const float4*)(ap);
        float4 a1 = *(const float4*)(ap + 4);
        at2[0] = (h2){(_Float16)a0.x, (_Float16)a0.y};
        at2[1] = (h2){(_Float16)a0.z, (_Float16)a0.w};
        at2[2] = (h2){(_Float16)a1.x, (_Float16)a1.y};
        at2[3] = (h2){(_Float16)a1.z, (_Float16)a1.w};
    }
    const _Float16 k02 = (_Float16)0.2f;

    const int rs = rowptr[v];
    const int re = rowptr[v + 1];

    float s = 0.f;
    h2 acch[4];
    #pragma unroll
    for (int q = 0; q < 4; ++q) acch[q] = (h2){(_Float16)0.f, (_Float16)0.f};

    #define CLAMPI(i) (((i) < re) ? (i) : rs)

    uint4 r0 = *(const uint4*)(xl + (size_t)csr_src[CLAMPI(rs + e2)]     * HC + choff);
    uint4 r1 = *(const uint4*)(xl + (size_t)csr_src[CLAMPI(rs + 2 + e2)] * HC + choff);
    int jn = csr_src[CLAMPI(rs + 4 + e2)];

    for (int k = rs; k < re; k += 4) {
        // ---------- stage A: pair k ----------
        {
            const uint4 cur = r0;
            r0 = *(const uint4*)(xl + (size_t)jn * HC + choff);     // pair k+4
            jn = csr_src[CLAMPI(k + 6 + e2)];                       // pair k+6
            const bool valid = (k + e2) < re;
            const h2* xh = (const h2*)&cur;
            h2 d2 = (h2){(_Float16)0.f, (_Float16)0.f};
            #pragma unroll
            for (int q = 0; q < 4; ++q) {
                h2 tt = xh[q] + xr2[q];
                h2 lk = __builtin_elementwise_max(tt, tt * k02);    // leaky_relu
                d2 += lk * at2[q];
            }
            float p = (float)d2.x + (float)d2.y;
            p += __shfl_xor(p, 1, 64);
            p += __shfl_xor(p, 2, 64);
            p += __shfl_xor(p, 4, 64);
            float pe = valid ? __expf(p) : 0.f;
            s += pe;
            const _Float16 peh = (_Float16)pe;
            const h2 pe2 = (h2){peh, peh};
            #pragma unroll
            for (int q = 0; q < 4; ++q)
                acch[q] += pe2 * xh[q];                             // pk_fma_f16
        }
        // ---------- stage B: pair k+2 ----------
        {
            const uint4 cur = r1;
            r1 = *(const uint4*)(xl + (size_t)jn * HC + choff);     // pair k+6
            jn = csr_src[CLAMPI(k + 8 + e2)];                       // pair k+8
            const bool valid = (k + 2 + e2) < re;
            const h2* xh = (const h2*)&cur;
            h2 d2 = (h2){(_Float16)0.f, (_Float16)0.f};
            #pragma unroll
            for (int q = 0; q < 4; ++q) {
                h2 tt = xh[q] + xr2[q];
                h2 lk = __builtin_elementwise_max(tt, tt * k02);    // leaky_relu
                d2 += lk * at2[q];
            }
            float p = (float)d2.x + (float)d2.y;
            p += __shfl_xor(p, 1, 64);
            p += __shfl_xor(p, 2, 64);
            p += __shfl_xor(p, 4, 64);
            float pe = valid ? __expf(p) : 0.f;
            s += pe;
            const _Float16 peh = (_Float16)pe;
            const h2 pe2 = (h2){peh, peh};
            #pragma unroll
            for (int q = 0; q < 4; ++q)
                acch[q] += pe2 * xh[q];                             // pk_fma_f16
        }
    }
    #undef CLAMPI

    // combine edge slots, normalize per head, then head-mean (in fp32)
    s += __shfl_xor(s, 32, 64);
    const float inv = 1.f / s;                          // deg>=1 (self-loop)
    float out8[8];
    #pragma unroll
    for (int q = 0; q < 8; ++q) {
        float av = (q & 1) ? (float)acch[q >> 1].y : (float)acch[q >> 1].x;
        float a = av + __shfl_xor(av, 32, 64);
        a *= inv;
        a += __shfl_xor(a, 8, 64);                      // sum over heads
        a += __shfl_xor(a, 16, 64);
        out8[q] = 0.25f * a;
    }
    if (l < 8) {
        const float4 cb0 = *(const float4*)(conv_bias + co * 8);
        const float4 cb1 = *(const float4*)(conv_bias + co * 8 + 4);
        float4 o0 = make_float4(out8[0] + cb0.x, out8[1] + cb0.y,
                                out8[2] + cb0.z, out8[3] + cb0.w);
        float4 o1 = make_float4(out8[4] + cb1.x, out8[5] + cb1.y,
                                out8[6] + cb1.z, out8[7] + cb1.w);
        float* op = h_out + (size_t)v * CC + co * 8;
        *(float4*)op       = o0;
        *(float4*)(op + 4) = o1;
    }
}

// ---------------------------------------------------------------------------
// per-channel sum / sumsq over nodes (hierarchical, 128 blocks, 16K atomics)
__global__ __launch_bounds__(256) void stats_kernel(const float* __restrict__ h,
                                                    float* __restrict__ stats, int n) {
    int t = threadIdx.x;
    int c = t & 63, r = t >> 6;
    float s = 0.f, s2 = 0.f;
    for (int node = blockIdx.x * 4 + r; node < n; node += gridDim.x * 4) {
        float v = h[node * CC + c];
        s += v; s2 += v * v;
    }
    __shared__ float l1[256], l2[256];
    l1[t] = s; l2[t] = s2;
    __syncthreads();
    if (t < 64) {
        s  = l1[t] + l1[64 + t] + l1[128 + t] + l1[192 + t];
        s2 = l2[t] + l2[64 + t] + l2[128 + t] + l2[192 + t];
        atomicAdd(&stats[c], s);
        atomicAdd(&stats[64 + c], s2);
    }
}

// ---------------------------------------------------------------------------
// GraphNorm (final layer only): x = (h - alpha*mu) * rsqrt(var+eps) * w + b
__global__ __launch_bounds__(256) void norm_kernel(const float* __restrict__ h,
                                                   const float* __restrict__ stats,
                                                   const float* __restrict__ gw,
                                                   const float* __restrict__ gs,
                                                   const float* __restrict__ gb,
                                                   float* __restrict__ out, int n) {
    __shared__ float na[64], nb[64];
    int t = threadIdx.x;
    if (t < 64) {
        float inv_n = 1.0f / (float)n;
        float mu  = stats[t] * inv_n;
        float eh2 = stats[64 + t] * inv_n;
        float a   = gs[t];
        float var = eh2 - 2.f * a * mu * mu + a * a * mu * mu;
        float rstd = rsqrtf(var + 1e-5f);
        na[t] = gw[t] * rstd;
        nb[t] = gb[t] - a * mu * gw[t] * rstd;
    }
    __syncthreads();
    int c = t & 63;
    float w = na[c], b = nb[c];
    int total = n * CC;
    for (int idx = blockIdx.x * 256 + t; idx < total; idx += gridDim.x * 256)
        out[idx] = fmaf(h[idx], w, b);
}

// ---------------------------------------------------------------------------
extern "C" void kernel_launch(void* const* d_in, const int* in_sizes, int n_in,
                              void* d_out, int out_size, void* d_ws, size_t ws_size,
                              hipStream_t stream) {
    const float* x0  = (const float*)d_in[0];
    const int*   ei  = (const int*)d_in[1];
    const float* Wl  = (const float*)d_in[2];
    const float* bl  = (const float*)d_in[3];
    const float* Wr  = (const float*)d_in[4];
    const float* br  = (const float*)d_in[5];
    const float* att = (const float*)d_in[6];
    const float* cb  = (const float*)d_in[7];
    const float* gw  = (const float*)d_in[8];
    const float* gs  = (const float*)d_in[9];
    const float* gb  = (const float*)d_in[10];

    const int n = in_sizes[0] / DD;      // 25000
    const int e = in_sizes[1] / 2;       // 400000
    const int* srcArr = ei;
    const int* dstArr = ei + e;

    char* w = (char*)d_ws;
    auto alloc = [&](size_t bytes) -> char* {
        char* p = w;
        w += (bytes + 255) & ~(size_t)255;
        return p;
    };
    __half* xl    = (__half*)alloc((size_t)n * HC * 2);
    __half* xr    = (__half*)alloc((size_t)n * HC * 2);
    float* hbuf   = (float*)alloc((size_t)n * CC * 4);
    int*   counts = (int*)  alloc((size_t)n * 4);
    int*   cursor = (int*)  alloc((size_t)n * 4);
    int*   rowptr = (int*)  alloc((size_t)(n + 1) * 4);
    int*   csr    = (int*)  alloc((size_t)(e + n + 2) * 4);
    float* stats  = (float*)alloc(NLAY * 128 * 4);

    const int tot = e + n;
    hipLaunchKernelGGL(zero_kernel,  dim3((n + 255) / 256),   dim3(256), 0, stream,
                       counts, cursor, stats, n);
    hipLaunchKernelGGL(count_kernel, dim3((tot + 255) / 256), dim3(256), 0, stream,
                       dstArr, counts, e, n);
    hipLaunchKernelGGL(scan_kernel,  dim3(1), dim3(1024), 0, stream,
                       counts, rowptr, n);
    hipLaunchKernelGGL(fill_kernel,  dim3((tot + 255) / 256), dim3(256), 0, stream,
                       srcArr, dstArr, rowptr, cursor, csr, e, n);

    for (int L = 0; L < NLAY; ++L) {
        const float* xin = (L == 0) ? x0 : hbuf;
        const int Lp = (L == 0) ? 0 : L - 1;
        const float* st = (L == 0) ? nullptr : stats + (size_t)Lp * 128;
        hipLaunchKernelGGL(proj_kernel, dim3((n + 63) / 64, 2), dim3(256), 0, stream,
                           xin, Wl + (size_t)L * HC * DD, bl + L * HC,
                           Wr + (size_t)L * HC * DD, br + L * HC, xl, xr, n,
                           st, gw + Lp * CC, gs + Lp * CC, gb + Lp * CC);
        hipLaunchKernelGGL(attn_kernel, dim3((n + 3) / 4), dim3(256), 0, stream,
                           xl, xr, att + L * HC, cb + L * CC, rowptr, csr, hbuf, n);
        hipLaunchKernelGGL(stats_kernel, dim3(128), dim3(256), 0, stream,
                           hbuf, stats + (size_t)L * 128, n);
    }
    hipLaunchKernelGGL(norm_kernel, dim3(512), dim3(256), 0, stream,
                       hbuf, stats + (size_t)(NLAY - 1) * 128, gw + (NLAY - 1) * CC,
                       gs + (NLAY - 1) * CC, gb + (NLAY - 1) * CC,
                       (float*)d_out, n);
}